// Round 5
// baseline (791.916 us; speedup 1.0000x reference)
//
#include <hip/hip_runtime.h>
#include <hip/hip_bf16.h>
#include <math.h>

#define NB 2
#define SS 3072
#define CC 1536
#define NH 12
#define DH 128
#define NTOK (NB * SS)
#define WE (CC * CC)         // 2,359,296
#define LOG2E 1.4426950408889634f

typedef __attribute__((ext_vector_type(8))) short short8;
typedef __attribute__((ext_vector_type(4))) float floatx4;

#define GLOAD(g, l) __builtin_amdgcn_global_load_lds( \
    (const __attribute__((address_space(1))) void*)(g), \
    (__attribute__((address_space(3))) void*)(l), 16, 0, 0)

__device__ __forceinline__ unsigned short f2bf(float f) {
    unsigned u = __float_as_uint(f);
    u += 0x7fffu + ((u >> 16) & 1u);   // RNE
    return (unsigned short)(u >> 16);
}
// XOR-swizzled chunk index in a [rows][4-chunk] LDS slab (16B chunks).
// rows r and r+8 alias (2-way, free), all else conflict-free.
__device__ __forceinline__ int swz(int row, int q) {
    return row * 4 + (q ^ ((row >> 1) & 3));
}

// ---------------------------------------------------------------------------
// Cast x (4*WE) + Wq,Wk,Wv,Wo (WE each) to one contiguous bf16 region.
// ---------------------------------------------------------------------------
__global__ __launch_bounds__(256) void cast_all(
    const float* __restrict__ x,
    const float* __restrict__ w0, const float* __restrict__ w1,
    const float* __restrict__ w2, const float* __restrict__ w3,
    unsigned short* __restrict__ o)
{
    const int y = blockIdx.y;
    const float* src = (y < 4) ? x + (size_t)y * WE
                     : (y == 4) ? w0 : (y == 5) ? w1 : (y == 6) ? w2 : w3;
    size_t i = ((size_t)blockIdx.x * 256 + threadIdx.x) * 4;
    float4 v = *(const float4*)&src[i];
    uint2 u;
    u.x = (unsigned)f2bf(v.x) | ((unsigned)f2bf(v.y) << 16);
    u.y = (unsigned)f2bf(v.z) | ((unsigned)f2bf(v.w) << 16);
    *(uint2*)&o[(size_t)y * WE + i] = u;
}

// ---------------------------------------------------------------------------
// RoPE angle table: tab[s*64+pj] = (cos, sin).
// ---------------------------------------------------------------------------
__global__ __launch_bounds__(256) void rope_table(
    const float* __restrict__ freqs, const int* __restrict__ gsz,
    float2* __restrict__ tab)
{
    const int id = blockIdx.x * 256 + threadIdx.x;   // 0..196607
    const int s = id >> 6, pj = id & 63;
    const int Hg = gsz[1], Wg = gsz[2];
    const int f = s / (Hg * Wg);
    const int rem = s - f * Hg * Wg;
    const int hh = rem / Wg;
    const int ww = rem - hh * Wg;
    const int row = (pj < 22) ? f : ((pj < 43) ? hh : ww);
    float sn, cs;
    sincosf(freqs[row * 64 + pj], &sn, &cs);
    tab[id] = make_float2(cs, sn);
}

// ---------------------------------------------------------------------------
// Fused QKV GEMM (swizzled LDS). jseg 0,1 -> bf16 (B,NH,S,DH); 2 -> (B,NH,DH,S).
// ---------------------------------------------------------------------------
__global__ __launch_bounds__(256) void qkv_gemm(
    const unsigned short* __restrict__ X,
    const unsigned short* __restrict__ Wqb, const unsigned short* __restrict__ Wkb,
    const unsigned short* __restrict__ Wvb,
    const float* __restrict__ bq, const float* __restrict__ bk,
    const float* __restrict__ bv,
    unsigned short* __restrict__ qo, unsigned short* __restrict__ ko,
    unsigned short* __restrict__ vto)
{
    __shared__ unsigned short As[128 * 32];
    __shared__ unsigned short Bs[128 * 32];
    const int tid = threadIdx.x;
    const int w = tid >> 6, l = tid & 63;
    const int jseg = blockIdx.y / 12;
    const unsigned short* Wt = (jseg == 0) ? Wqb : (jseg == 1) ? Wkb : Wvb;
    const float* bias        = (jseg == 0) ? bq  : (jseg == 1) ? bk  : bv;
    unsigned short* Y        = (jseg == 0) ? qo  : (jseg == 1) ? ko  : vto;
    const int i0 = blockIdx.x * 128, j0 = (blockIdx.y % 12) * 128;
    const int srow = tid >> 2;
    const int gk8 = (((tid & 3) ^ ((srow >> 1) & 3))) * 8;   // swizzled global chunk

    floatx4 acc[4][4] = {};
    for (int k0 = 0; k0 < CC; k0 += 32) {
        __syncthreads();
        GLOAD(X + (size_t)(i0 + srow) * CC + k0 + gk8,        As + (size_t)tid * 8);
        GLOAD(X + (size_t)(i0 + 64 + srow) * CC + k0 + gk8,   As + (size_t)(256 + tid) * 8);
        GLOAD(Wt + (size_t)(j0 + srow) * CC + k0 + gk8,       Bs + (size_t)tid * 8);
        GLOAD(Wt + (size_t)(j0 + 64 + srow) * CC + k0 + gk8,  Bs + (size_t)(256 + tid) * 8);
        __syncthreads();
        const int wr = (w >> 1) * 64, wc = (w & 1) * 64;
        short8 af[4], bf[4];
        #pragma unroll
        for (int mb = 0; mb < 4; ++mb)
            af[mb] = *(const short8*)&As[swz(wr + mb * 16 + (l & 15), l >> 4) * 8];
        #pragma unroll
        for (int nb = 0; nb < 4; ++nb)
            bf[nb] = *(const short8*)&Bs[swz(wc + nb * 16 + (l & 15), l >> 4) * 8];
        #pragma unroll
        for (int mb = 0; mb < 4; ++mb)
            #pragma unroll
            for (int nb = 0; nb < 4; ++nb)
                acc[mb][nb] = __builtin_amdgcn_mfma_f32_16x16x32_bf16(
                    af[mb], bf[nb], acc[mb][nb], 0, 0, 0);
    }

    const int wr = (w >> 1) * 64, wc = (w & 1) * 64;
    #pragma unroll
    for (int mb = 0; mb < 4; ++mb)
        #pragma unroll
        for (int nb = 0; nb < 4; ++nb) {
            const int n = j0 + wc + nb * 16 + (l & 15);
            const float bv2 = bias[n];
            const int h = n >> 7, td = n & 127;
            #pragma unroll
            for (int r = 0; r < 4; ++r) {
                const int m = i0 + wr + mb * 16 + (l >> 4) * 4 + r;
                const float val = acc[mb][nb][r] + bv2;
                const int b = (m >= SS) ? 1 : 0;
                const int s = m - b * SS;
                if (jseg < 2)
                    Y[((size_t)(b * NH + h) * SS + s) * DH + td] = f2bf(val);
                else
                    Y[((size_t)(b * NH + h) * DH + td) * SS + s] = f2bf(val);
            }
        }
}

// ---------------------------------------------------------------------------
// O-projection (swizzled LDS): fp32 out (B,S,C) = A @ Wo^T + bo.
// ---------------------------------------------------------------------------
__global__ __launch_bounds__(256) void gemm_o(
    const unsigned short* __restrict__ X, const unsigned short* __restrict__ Wt,
    const float* __restrict__ bias, float* __restrict__ Y)
{
    __shared__ unsigned short As[128 * 32];
    __shared__ unsigned short Bs[128 * 32];
    const int tid = threadIdx.x;
    const int w = tid >> 6, l = tid & 63;
    const int i0 = blockIdx.x * 128, j0 = blockIdx.y * 128;
    const int srow = tid >> 2;
    const int gk8 = (((tid & 3) ^ ((srow >> 1) & 3))) * 8;

    floatx4 acc[4][4] = {};
    for (int k0 = 0; k0 < CC; k0 += 32) {
        __syncthreads();
        GLOAD(X + (size_t)(i0 + srow) * CC + k0 + gk8,        As + (size_t)tid * 8);
        GLOAD(X + (size_t)(i0 + 64 + srow) * CC + k0 + gk8,   As + (size_t)(256 + tid) * 8);
        GLOAD(Wt + (size_t)(j0 + srow) * CC + k0 + gk8,       Bs + (size_t)tid * 8);
        GLOAD(Wt + (size_t)(j0 + 64 + srow) * CC + k0 + gk8,  Bs + (size_t)(256 + tid) * 8);
        __syncthreads();
        const int wr = (w >> 1) * 64, wc = (w & 1) * 64;
        short8 af[4], bf[4];
        #pragma unroll
        for (int mb = 0; mb < 4; ++mb)
            af[mb] = *(const short8*)&As[swz(wr + mb * 16 + (l & 15), l >> 4) * 8];
        #pragma unroll
        for (int nb = 0; nb < 4; ++nb)
            bf[nb] = *(const short8*)&Bs[swz(wc + nb * 16 + (l & 15), l >> 4) * 8];
        #pragma unroll
        for (int mb = 0; mb < 4; ++mb)
            #pragma unroll
            for (int nb = 0; nb < 4; ++nb)
                acc[mb][nb] = __builtin_amdgcn_mfma_f32_16x16x32_bf16(
                    af[mb], bf[nb], acc[mb][nb], 0, 0, 0);
    }

    const int wr = (w >> 1) * 64, wc = (w & 1) * 64;
    #pragma unroll
    for (int mb = 0; mb < 4; ++mb)
        #pragma unroll
        for (int nb = 0; nb < 4; ++nb) {
            const int n = j0 + wc + nb * 16 + (l & 15);
            const float bv = bias[n];
            #pragma unroll
            for (int r = 0; r < 4; ++r) {
                const int m = i0 + wr + mb * 16 + (l >> 4) * 4 + r;
                Y[(size_t)m * CC + n] = acc[mb][nb][r] + bv;
            }
        }
}

// ---------------------------------------------------------------------------
// Fused RMSNorm + RoPE (table-driven), in-place bf16 (B,NH,S,DH).
// ---------------------------------------------------------------------------
__global__ __launch_bounds__(256) void norm_rope(
    unsigned short* __restrict__ qb, unsigned short* __restrict__ kb,
    const float* __restrict__ nqw, const float* __restrict__ nkw,
    const float2* __restrict__ tab)
{
    const int bid = blockIdx.x;
    const int which = (bid >= NTOK) ? 1 : 0;
    const int tok = bid - which * NTOK;
    unsigned short* t    = which ? kb : qb;
    const float* wgt     = which ? nkw : nqw;
    const float outscale = which ? 1.0f : 0.08838834764831845f * LOG2E;
    const int b = tok / SS, s = tok - b * SS;
    const int tid = threadIdx.x;

    float2 vals[3];
    size_t addrs[3];
    float ss = 0.f;
    #pragma unroll
    for (int kt = 0; kt < 3; ++kt) {
        int p = tid + kt * 256;
        int h = p >> 6, pj = p & 63;
        size_t addr = ((size_t)(b * NH + h) * SS + s) * DH + 2 * pj;
        addrs[kt] = addr;
        unsigned u = *(const unsigned*)&t[addr];
        float2 v;
        v.x = __uint_as_float(u << 16);
        v.y = __uint_as_float(u & 0xffff0000u);
        vals[kt] = v;
        ss += v.x * v.x + v.y * v.y;
    }
    #pragma unroll
    for (int off = 32; off > 0; off >>= 1) ss += __shfl_down(ss, off, 64);
    __shared__ float red[4];
    if ((tid & 63) == 0) red[tid >> 6] = ss;
    __syncthreads();
    const float total = red[0] + red[1] + red[2] + red[3];
    const float rstd = rsqrtf(total * (1.0f / CC) + 1e-6f) * outscale;

    #pragma unroll
    for (int kt = 0; kt < 3; ++kt) {
        int p = tid + kt * 256;
        int h = p >> 6, pj = p & 63;
        float2 cssn = tab[s * 64 + pj];
        int ch = h * DH + 2 * pj;
        float te = vals[kt].x * rstd * wgt[ch];
        float to = vals[kt].y * rstd * wgt[ch + 1];
        unsigned o = (unsigned)f2bf(te * cssn.x - to * cssn.y) |
                     ((unsigned)f2bf(te * cssn.y + to * cssn.x) << 16);
        *(unsigned*)&t[addrs[kt]] = o;
    }
}

// ---------------------------------------------------------------------------
// MFMA flash attention, register-prefetch pipelined.
// K/V for tile kt+1 are buffer_load'ed into VGPRs during tile kt's compute
// (plain register loads -> barrier does NOT drain them; vmcnt never hits 0
// on the critical path). ds_write_b128 regs->LDS at loop top (single buffer).
// 128-row Q tile, wave owns 32 rows (rb=2 blocking), swizzled LDS, no-max
// softmax (bounded logits, q pre-scaled by 1/sqrt(d)*log2e), packed bf16 cvt.
// LDS 50 KB: Q staging aliases the K/V buffer.
// ---------------------------------------------------------------------------
__global__ __launch_bounds__(256, 2) void flash_attn_mfma(
    const unsigned short* __restrict__ qg, const unsigned short* __restrict__ kg,
    const unsigned short* __restrict__ vg, const int* __restrict__ seq_lens,
    unsigned short* __restrict__ out)
{
    __shared__ unsigned short lds[25600];        // 50 KB
    unsigned short* Ks = lds;                    // [kc][key][32] swizzled, 16 KB
    unsigned short* Vs = lds + 8192;             // [ks][dcol][32] swizzled, 16 KB
    // Q staging (32 KB) aliases Ks+Vs; P slabs are separate:
    const int tid = threadIdx.x;
    const int w = tid >> 6, l = tid & 63;
    unsigned short* Psw = lds + 16384 + w * (32 * 72);   // 4 x 4.5 KB

    const int bid = blockIdx.x;
    const int qt = bid / (NB * NH);
    const int rem0 = bid - qt * (NB * NH);
    const int h = rem0 >> 1;
    const int b = rem0 & 1;
    const int slen = seq_lens[b];
    const int s0 = qt * 128;

    const unsigned short* qbase = qg + ((size_t)(b * NH + h) * SS + s0) * DH;
    const unsigned short* kbase = kg + ((size_t)(b * NH + h) * SS) * DH;
    const unsigned short* vbase = vg + ((size_t)(b * NH + h) * DH) * SS;

    // ---- stage Q (GLOAD into aliased region), pull frags to registers ----
    #pragma unroll
    for (int i = 0; i < 8; ++i) {
        int cid = i * 256 + tid;
        int kc = cid >> 9, r2 = cid & 511, row = r2 >> 2, sq = r2 & 3;
        GLOAD(qbase + (size_t)row * DH + kc * 32 + (sq ^ ((row >> 1) & 3)) * 8,
              lds + (size_t)cid * 8);
    }
    __syncthreads();
    short8 qf[2][4];
    #pragma unroll
    for (int rb = 0; rb < 2; ++rb)
        #pragma unroll
        for (int kc = 0; kc < 4; ++kc)
            qf[rb][kc] = *(const short8*)&lds[(kc * 512 + swz(w * 32 + rb * 16 + (l & 15), l >> 4)) * 8];

    // ---- per-thread K/V staging source offsets (elements) ----
    int koff[4], voff[4];
    #pragma unroll
    for (int i = 0; i < 4; ++i) {
        int cid = i * 256 + tid;
        {   // K: [kc(2b)][row(6b)][chunk(2b)]
            int kc = cid >> 8, r2 = cid & 255, row = r2 >> 2, sq = r2 & 3;
            koff[i] = row * DH + kc * 32 + (sq ^ ((row >> 1) & 3)) * 8;
        }
        {   // V: [ks(1b)][dcol(7b)][chunk(2b)]
            int ks = cid >> 9, r2 = cid & 511, dc = r2 >> 2, sq = r2 & 3;
            voff[i] = dc * SS + ks * 32 + (sq ^ ((dc >> 1) & 3)) * 8;
        }
    }

    // ---- prologue: load tile 0 into registers ----
    uint4 kreg[4], vreg[4];
    #pragma unroll
    for (int i = 0; i < 4; ++i) {
        kreg[i] = *(const uint4*)(kbase + koff[i]);
        vreg[i] = *(const uint4*)(vbase + voff[i]);
    }

    floatx4 acc[2][8] = {};
    float lsum[2][4] = {};
    const int ntiles = (slen + 63) >> 6;

    for (int kt = 0; kt < ntiles; ++kt) {
        __syncthreads();    // prior compute's LDS reads done (Q frags on kt==0)
        #pragma unroll
        for (int i = 0; i < 4; ++i) {
            int cid = i * 256 + tid;
            *(uint4*)&Ks[(size_t)cid * 8] = kreg[i];
            *(uint4*)&Vs[(size_t)cid * 8] = vreg[i];
        }
        if (kt + 1 < ntiles) {      // prefetch next tile -> registers (stays in flight)
            const unsigned short* kb2 = kbase + (size_t)(kt + 1) * 64 * DH;
            const unsigned short* vb2 = vbase + (size_t)(kt + 1) * 64;
            #pragma unroll
            for (int i = 0; i < 4; ++i) {
                kreg[i] = *(const uint4*)(kb2 + koff[i]);
                vreg[i] = *(const uint4*)(vb2 + voff[i]);
            }
        }
        __syncthreads();    // K/V tile visible

        // S = Q K^T : per wave 32 q-rows x 64 keys; K frags shared across rb
        floatx4 sv[2][4] = {};
        #pragma unroll
        for (int kc = 0; kc < 4; ++kc) {
            short8 kf[4];
            #pragma unroll
            for (int nb = 0; nb < 4; ++nb)
                kf[nb] = *(const short8*)&Ks[(kc * 256 + swz(nb * 16 + (l & 15), l >> 4)) * 8];
            #pragma unroll
            for (int rb = 0; rb < 2; ++rb)
                #pragma unroll
                for (int nb = 0; nb < 4; ++nb)
                    sv[rb][nb] = __builtin_amdgcn_mfma_f32_16x16x32_bf16(
                        qf[rb][kc], kf[nb], sv[rb][nb], 0, 0, 0);
        }

        // p = exp2(s); mask only the single partial tile; packed bf16 cvt
        const int valid = slen - kt * 64;
        #pragma unroll
        for (int rb = 0; rb < 2; ++rb) {
            if (valid >= 64) {
                #pragma unroll
                for (int nb = 0; nb < 4; ++nb)
                    #pragma unroll
                    for (int r = 0; r < 4; ++r)
                        sv[rb][nb][r] = exp2f(sv[rb][nb][r]);
            } else {
                #pragma unroll
                for (int nb = 0; nb < 4; ++nb) {
                    const int key = nb * 16 + (l & 15);
                    #pragma unroll
                    for (int r = 0; r < 4; ++r)
                        sv[rb][nb][r] = (key < valid) ? exp2f(sv[rb][nb][r]) : 0.0f;
                }
            }
            #pragma unroll
            for (int r = 0; r < 4; ++r)
                lsum[rb][r] += sv[rb][0][r] + sv[rb][1][r] + sv[rb][2][r] + sv[rb][3][r];
            #pragma unroll
            for (int nb = 0; nb < 4; ++nb)
                #pragma unroll
                for (int r = 0; r < 4; r += 2) {
                    union { __hip_bfloat162 v; ushort2 u; } cv;
                    cv.v = __float22bfloat162_rn(
                        make_float2(sv[rb][nb][r], sv[rb][nb][r + 1]));
                    const int rowb = rb * 16 + (l >> 4) * 4 + r;
                    Psw[rowb * 72 + nb * 16 + (l & 15)]       = cv.u.x;
                    Psw[(rowb + 1) * 72 + nb * 16 + (l & 15)] = cv.u.y;
                }
        }

        // O += P V : V frags shared across rb
        #pragma unroll
        for (int ks = 0; ks < 2; ++ks) {
            short8 pa[2];
            #pragma unroll
            for (int rb = 0; rb < 2; ++rb)
                pa[rb] = *(const short8*)&Psw[(rb * 16 + (l & 15)) * 72 + ks * 32 + (l >> 4) * 8];
            #pragma unroll
            for (int nb2 = 0; nb2 < 8; ++nb2) {
                short8 vf = *(const short8*)&Vs[(ks * 512 + swz(nb2 * 16 + (l & 15), l >> 4)) * 8];
                #pragma unroll
                for (int rb = 0; rb < 2; ++rb)
                    acc[rb][nb2] = __builtin_amdgcn_mfma_f32_16x16x32_bf16(
                        pa[rb], vf, acc[rb][nb2], 0, 0, 0);
            }
        }
    }

    #pragma unroll
    for (int rb = 0; rb < 2; ++rb) {
        float rl[4];
        #pragma unroll
        for (int r = 0; r < 4; ++r) {
            float s = lsum[rb][r];
            #pragma unroll
            for (int mm = 1; mm < 16; mm <<= 1) s += __shfl_xor(s, mm, 64);
            rl[r] = 1.0f / s;
        }
        #pragma unroll
        for (int nb2 = 0; nb2 < 8; ++nb2) {
            const int col = h * DH + nb2 * 16 + (l & 15);
            #pragma unroll
            for (int r = 0; r < 4; ++r) {
                const int srow = s0 + w * 32 + rb * 16 + (l >> 4) * 4 + r;
                out[((size_t)b * SS + srow) * CC + col] = f2bf(acc[rb][nb2][r] * rl[r]);
            }
        }
    }
}

// ---------------------------------------------------------------------------
extern "C" void kernel_launch(void* const* d_in, const int* in_sizes, int n_in,
                              void* d_out, int out_size, void* d_ws, size_t ws_size,
                              hipStream_t stream) {
    const float* x          = (const float*)d_in[0];
    const int*   seq_lens   = (const int*)d_in[1];
    const int*   grid_sizes = (const int*)d_in[2];
    const float* freqs      = (const float*)d_in[3];
    const float* Wq         = (const float*)d_in[4];
    const float* bq         = (const float*)d_in[5];
    const float* Wk         = (const float*)d_in[6];
    const float* bk         = (const float*)d_in[7];
    const float* Wv         = (const float*)d_in[8];
    const float* bv         = (const float*)d_in[9];
    const float* Wo         = (const float*)d_in[10];
    const float* bo         = (const float*)d_in[11];
    const float* nqw        = (const float*)d_in[12];
    const float* nkw        = (const float*)d_in[13];
    float* out = (float*)d_out;

    const size_t TE = (size_t)NTOK * CC;   // 9,437,184 (= 4*WE)
    unsigned short* xb  = (unsigned short*)d_ws;   // xb..wob contiguous
    unsigned short* wqb = xb + TE;
    unsigned short* wkb = wqb + WE;
    unsigned short* wvb = wkb + WE;
    unsigned short* wob = wvb + WE;
    unsigned short* qb  = wob + WE;
    unsigned short* kb  = qb + TE;
    unsigned short* vtb = kb + TE;
    unsigned short* ab  = vtb + TE;
    float2* tab = (float2*)(ab + TE);      // 3072*64 float2 = 1.5 MB

    cast_all<<<dim3(WE / 1024, 8), 256, 0, stream>>>(x, Wq, Wk, Wv, Wo, xb);
    rope_table<<<dim3(SS * 64 / 256), 256, 0, stream>>>(freqs, grid_sizes, tab);

    qkv_gemm<<<dim3(NTOK / 128, 36), 256, 0, stream>>>(
        xb, wqb, wkb, wvb, bq, bk, bv, qb, kb, vtb);

    norm_rope<<<dim3(2 * NTOK), 256, 0, stream>>>(qb, kb, nqw, nkw, tab);

    flash_attn_mfma<<<dim3(NB * NH * (SS / 128)), 256, 0, stream>>>(qb, kb, vtb, seq_lens, ab);

    gemm_o<<<dim3(NTOK / 128, CC / 128), 256, 0, stream>>>(ab, wob, bo, out);
}

// Round 6
// 523.144 us; speedup vs baseline: 1.5138x; 1.5138x over previous
//
#include <hip/hip_runtime.h>
#include <hip/hip_bf16.h>
#include <math.h>

#define NB 2
#define SS 3072
#define CC 1536
#define NH 12
#define DH 128
#define NTOK (NB * SS)
#define WE (CC * CC)         // 2,359,296
#define LOG2E 1.4426950408889634f

typedef __attribute__((ext_vector_type(8))) short short8;
typedef __attribute__((ext_vector_type(4))) float floatx4;

#define GLOAD(g, l) __builtin_amdgcn_global_load_lds( \
    (const __attribute__((address_space(1))) void*)(g), \
    (__attribute__((address_space(3))) void*)(l), 16, 0, 0)

__device__ __forceinline__ unsigned short f2bf(float f) {
    unsigned u = __float_as_uint(f);
    u += 0x7fffu + ((u >> 16) & 1u);   // RNE
    return (unsigned short)(u >> 16);
}
// XOR-swizzled chunk index in a [rows][4-chunk] LDS slab (16B chunks).
// rows r and r+8 alias (2-way, free), all else conflict-free.
__device__ __forceinline__ int swz(int row, int q) {
    return row * 4 + (q ^ ((row >> 1) & 3));
}

// ---------------------------------------------------------------------------
// Cast x (4*WE) + Wq,Wk,Wv,Wo (WE each) to one contiguous bf16 region.
// ---------------------------------------------------------------------------
__global__ __launch_bounds__(256) void cast_all(
    const float* __restrict__ x,
    const float* __restrict__ w0, const float* __restrict__ w1,
    const float* __restrict__ w2, const float* __restrict__ w3,
    unsigned short* __restrict__ o)
{
    const int y = blockIdx.y;
    const float* src = (y < 4) ? x + (size_t)y * WE
                     : (y == 4) ? w0 : (y == 5) ? w1 : (y == 6) ? w2 : w3;
    size_t i = ((size_t)blockIdx.x * 256 + threadIdx.x) * 4;
    float4 v = *(const float4*)&src[i];
    uint2 u;
    u.x = (unsigned)f2bf(v.x) | ((unsigned)f2bf(v.y) << 16);
    u.y = (unsigned)f2bf(v.z) | ((unsigned)f2bf(v.w) << 16);
    *(uint2*)&o[(size_t)y * WE + i] = u;
}

// ---------------------------------------------------------------------------
// RoPE angle table: tab[s*64+pj] = (cos, sin).
// ---------------------------------------------------------------------------
__global__ __launch_bounds__(256) void rope_table(
    const float* __restrict__ freqs, const int* __restrict__ gsz,
    float2* __restrict__ tab)
{
    const int id = blockIdx.x * 256 + threadIdx.x;   // 0..196607
    const int s = id >> 6, pj = id & 63;
    const int Hg = gsz[1], Wg = gsz[2];
    const int f = s / (Hg * Wg);
    const int rem = s - f * Hg * Wg;
    const int hh = rem / Wg;
    const int ww = rem - hh * Wg;
    const int row = (pj < 22) ? f : ((pj < 43) ? hh : ww);
    float sn, cs;
    sincosf(freqs[row * 64 + pj], &sn, &cs);
    tab[id] = make_float2(cs, sn);
}

// ---------------------------------------------------------------------------
// Fused QKV GEMM (swizzled LDS). jseg 0,1 -> bf16 (B,NH,S,DH); 2 -> (B,NH,DH,S).
// ---------------------------------------------------------------------------
__global__ __launch_bounds__(256) void qkv_gemm(
    const unsigned short* __restrict__ X,
    const unsigned short* __restrict__ Wqb, const unsigned short* __restrict__ Wkb,
    const unsigned short* __restrict__ Wvb,
    const float* __restrict__ bq, const float* __restrict__ bk,
    const float* __restrict__ bv,
    unsigned short* __restrict__ qo, unsigned short* __restrict__ ko,
    unsigned short* __restrict__ vto)
{
    __shared__ unsigned short As[128 * 32];
    __shared__ unsigned short Bs[128 * 32];
    const int tid = threadIdx.x;
    const int w = tid >> 6, l = tid & 63;
    const int jseg = blockIdx.y / 12;
    const unsigned short* Wt = (jseg == 0) ? Wqb : (jseg == 1) ? Wkb : Wvb;
    const float* bias        = (jseg == 0) ? bq  : (jseg == 1) ? bk  : bv;
    unsigned short* Y        = (jseg == 0) ? qo  : (jseg == 1) ? ko  : vto;
    const int i0 = blockIdx.x * 128, j0 = (blockIdx.y % 12) * 128;
    const int srow = tid >> 2;
    const int gk8 = (((tid & 3) ^ ((srow >> 1) & 3))) * 8;   // swizzled global chunk

    floatx4 acc[4][4] = {};
    for (int k0 = 0; k0 < CC; k0 += 32) {
        __syncthreads();
        GLOAD(X + (size_t)(i0 + srow) * CC + k0 + gk8,        As + (size_t)tid * 8);
        GLOAD(X + (size_t)(i0 + 64 + srow) * CC + k0 + gk8,   As + (size_t)(256 + tid) * 8);
        GLOAD(Wt + (size_t)(j0 + srow) * CC + k0 + gk8,       Bs + (size_t)tid * 8);
        GLOAD(Wt + (size_t)(j0 + 64 + srow) * CC + k0 + gk8,  Bs + (size_t)(256 + tid) * 8);
        __syncthreads();
        const int wr = (w >> 1) * 64, wc = (w & 1) * 64;
        short8 af[4], bf[4];
        #pragma unroll
        for (int mb = 0; mb < 4; ++mb)
            af[mb] = *(const short8*)&As[swz(wr + mb * 16 + (l & 15), l >> 4) * 8];
        #pragma unroll
        for (int nb = 0; nb < 4; ++nb)
            bf[nb] = *(const short8*)&Bs[swz(wc + nb * 16 + (l & 15), l >> 4) * 8];
        #pragma unroll
        for (int mb = 0; mb < 4; ++mb)
            #pragma unroll
            for (int nb = 0; nb < 4; ++nb)
                acc[mb][nb] = __builtin_amdgcn_mfma_f32_16x16x32_bf16(
                    af[mb], bf[nb], acc[mb][nb], 0, 0, 0);
    }

    const int wr = (w >> 1) * 64, wc = (w & 1) * 64;
    #pragma unroll
    for (int mb = 0; mb < 4; ++mb)
        #pragma unroll
        for (int nb = 0; nb < 4; ++nb) {
            const int n = j0 + wc + nb * 16 + (l & 15);
            const float bv2 = bias[n];
            const int h = n >> 7, td = n & 127;
            #pragma unroll
            for (int r = 0; r < 4; ++r) {
                const int m = i0 + wr + mb * 16 + (l >> 4) * 4 + r;
                const float val = acc[mb][nb][r] + bv2;
                const int b = (m >= SS) ? 1 : 0;
                const int s = m - b * SS;
                if (jseg < 2)
                    Y[((size_t)(b * NH + h) * SS + s) * DH + td] = f2bf(val);
                else
                    Y[((size_t)(b * NH + h) * DH + td) * SS + s] = f2bf(val);
            }
        }
}

// ---------------------------------------------------------------------------
// O-projection (swizzled LDS): fp32 out (B,S,C) = A @ Wo^T + bo.
// ---------------------------------------------------------------------------
__global__ __launch_bounds__(256) void gemm_o(
    const unsigned short* __restrict__ X, const unsigned short* __restrict__ Wt,
    const float* __restrict__ bias, float* __restrict__ Y)
{
    __shared__ unsigned short As[128 * 32];
    __shared__ unsigned short Bs[128 * 32];
    const int tid = threadIdx.x;
    const int w = tid >> 6, l = tid & 63;
    const int i0 = blockIdx.x * 128, j0 = blockIdx.y * 128;
    const int srow = tid >> 2;
    const int gk8 = (((tid & 3) ^ ((srow >> 1) & 3))) * 8;

    floatx4 acc[4][4] = {};
    for (int k0 = 0; k0 < CC; k0 += 32) {
        __syncthreads();
        GLOAD(X + (size_t)(i0 + srow) * CC + k0 + gk8,        As + (size_t)tid * 8);
        GLOAD(X + (size_t)(i0 + 64 + srow) * CC + k0 + gk8,   As + (size_t)(256 + tid) * 8);
        GLOAD(Wt + (size_t)(j0 + srow) * CC + k0 + gk8,       Bs + (size_t)tid * 8);
        GLOAD(Wt + (size_t)(j0 + 64 + srow) * CC + k0 + gk8,  Bs + (size_t)(256 + tid) * 8);
        __syncthreads();
        const int wr = (w >> 1) * 64, wc = (w & 1) * 64;
        short8 af[4], bf[4];
        #pragma unroll
        for (int mb = 0; mb < 4; ++mb)
            af[mb] = *(const short8*)&As[swz(wr + mb * 16 + (l & 15), l >> 4) * 8];
        #pragma unroll
        for (int nb = 0; nb < 4; ++nb)
            bf[nb] = *(const short8*)&Bs[swz(wc + nb * 16 + (l & 15), l >> 4) * 8];
        #pragma unroll
        for (int mb = 0; mb < 4; ++mb)
            #pragma unroll
            for (int nb = 0; nb < 4; ++nb)
                acc[mb][nb] = __builtin_amdgcn_mfma_f32_16x16x32_bf16(
                    af[mb], bf[nb], acc[mb][nb], 0, 0, 0);
    }

    const int wr = (w >> 1) * 64, wc = (w & 1) * 64;
    #pragma unroll
    for (int mb = 0; mb < 4; ++mb)
        #pragma unroll
        for (int nb = 0; nb < 4; ++nb) {
            const int n = j0 + wc + nb * 16 + (l & 15);
            const float bv = bias[n];
            #pragma unroll
            for (int r = 0; r < 4; ++r) {
                const int m = i0 + wr + mb * 16 + (l >> 4) * 4 + r;
                Y[(size_t)m * CC + n] = acc[mb][nb][r] + bv;
            }
        }
}

// ---------------------------------------------------------------------------
// Fused RMSNorm + RoPE (table-driven), in-place bf16 (B,NH,S,DH).
// ---------------------------------------------------------------------------
__global__ __launch_bounds__(256) void norm_rope(
    unsigned short* __restrict__ qb, unsigned short* __restrict__ kb,
    const float* __restrict__ nqw, const float* __restrict__ nkw,
    const float2* __restrict__ tab)
{
    const int bid = blockIdx.x;
    const int which = (bid >= NTOK) ? 1 : 0;
    const int tok = bid - which * NTOK;
    unsigned short* t    = which ? kb : qb;
    const float* wgt     = which ? nkw : nqw;
    const float outscale = which ? 1.0f : 0.08838834764831845f * LOG2E;
    const int b = tok / SS, s = tok - b * SS;
    const int tid = threadIdx.x;

    float2 vals[3];
    size_t addrs[3];
    float ss = 0.f;
    #pragma unroll
    for (int kt = 0; kt < 3; ++kt) {
        int p = tid + kt * 256;
        int h = p >> 6, pj = p & 63;
        size_t addr = ((size_t)(b * NH + h) * SS + s) * DH + 2 * pj;
        addrs[kt] = addr;
        unsigned u = *(const unsigned*)&t[addr];
        float2 v;
        v.x = __uint_as_float(u << 16);
        v.y = __uint_as_float(u & 0xffff0000u);
        vals[kt] = v;
        ss += v.x * v.x + v.y * v.y;
    }
    #pragma unroll
    for (int off = 32; off > 0; off >>= 1) ss += __shfl_down(ss, off, 64);
    __shared__ float red[4];
    if ((tid & 63) == 0) red[tid >> 6] = ss;
    __syncthreads();
    const float total = red[0] + red[1] + red[2] + red[3];
    const float rstd = rsqrtf(total * (1.0f / CC) + 1e-6f) * outscale;

    #pragma unroll
    for (int kt = 0; kt < 3; ++kt) {
        int p = tid + kt * 256;
        int h = p >> 6, pj = p & 63;
        float2 cssn = tab[s * 64 + pj];
        int ch = h * DH + 2 * pj;
        float te = vals[kt].x * rstd * wgt[ch];
        float to = vals[kt].y * rstd * wgt[ch + 1];
        unsigned o = (unsigned)f2bf(te * cssn.x - to * cssn.y) |
                     ((unsigned)f2bf(te * cssn.y + to * cssn.x) << 16);
        *(unsigned*)&t[addrs[kt]] = o;
    }
}

// ---------------------------------------------------------------------------
// MFMA flash attention, double-buffered GLOAD pipeline, ONE barrier/iter.
//   top-of-loop barrier drains tile kt's GLOADs (in flight during compute
//   of kt-1); prefetch for kt+1 issued right after, overlapping compute kt.
// 128-row Q tile, wave owns 32 rows (rb=2), swizzled LDS, no-max softmax
// (bounded logits, q pre-scaled by 1/sqrt(d)*log2e), P slab 16 rows/wave
// (rb processed sequentially; per-wave DS ops are in-order).
// LDS = 2x32 KB KV + 9 KB P = 73 KB -> 2 blocks/CU. Q stages through buf0.
// ---------------------------------------------------------------------------
__global__ __launch_bounds__(256, 2) void flash_attn_mfma(
    const unsigned short* __restrict__ qg, const unsigned short* __restrict__ kg,
    const unsigned short* __restrict__ vg, const int* __restrict__ seq_lens,
    unsigned short* __restrict__ out)
{
    __shared__ unsigned short lds[37376];    // 73 KB
    const int tid = threadIdx.x;
    const int w = tid >> 6, l = tid & 63;
    unsigned short* Psw = lds + 32768 + w * (16 * 72);

    const int bid = blockIdx.x;
    const int qt = bid / (NB * NH);
    const int rem0 = bid - qt * (NB * NH);
    const int h = rem0 >> 1;
    const int b = rem0 & 1;
    const int slen = seq_lens[b];
    const int s0 = qt * 128;

    const unsigned short* qbase = qg + ((size_t)(b * NH + h) * SS + s0) * DH;
    const unsigned short* kbase = kg + ((size_t)(b * NH + h) * SS) * DH;
    const unsigned short* vbase = vg + ((size_t)(b * NH + h) * DH) * SS;

    // ---- stage Q through buf0 region, pull frags to registers ----
    #pragma unroll
    for (int i = 0; i < 8; ++i) {
        int cid = i * 256 + tid;
        int kc = cid >> 9, r2 = cid & 511, row = r2 >> 2, sq = r2 & 3;
        GLOAD(qbase + (size_t)row * DH + kc * 32 + (sq ^ ((row >> 1) & 3)) * 8,
              lds + (size_t)cid * 8);
    }
    __syncthreads();
    short8 qf[2][4];
    #pragma unroll
    for (int rb = 0; rb < 2; ++rb)
        #pragma unroll
        for (int kc = 0; kc < 4; ++kc)
            qf[rb][kc] = *(const short8*)&lds[(kc * 512 + swz(w * 32 + rb * 16 + (l & 15), l >> 4)) * 8];
    __syncthreads();   // all waves' Q-frag reads done before buf0 is overwritten

    // per-thread chunk descriptors for K/V staging
    int ksrc[4], vsrc[4];
    #pragma unroll
    for (int i = 0; i < 4; ++i) {
        int cid = i * 256 + tid;
        {   int kc = cid >> 8, r2 = cid & 255, row = r2 >> 2, sq = r2 & 3;
            ksrc[i] = row * DH + kc * 32 + (sq ^ ((row >> 1) & 3)) * 8; }
        {   int ks = cid >> 9, r2 = cid & 511, dc = r2 >> 2, sq = r2 & 3;
            vsrc[i] = dc * SS + ks * 32 + (sq ^ ((dc >> 1) & 3)) * 8; }
    }

    const int ntiles = (slen + 63) >> 6;

    // prologue: GLOAD tile 0 -> buf0
    #pragma unroll
    for (int i = 0; i < 4; ++i) {
        int cid = i * 256 + tid;
        GLOAD(kbase + ksrc[i],        lds + (size_t)cid * 8);
        GLOAD(vbase + vsrc[i],        lds + 8192 + (size_t)cid * 8);
    }

    floatx4 acc[2][8] = {};
    float lsum[2][4] = {};

    for (int kt = 0; kt < ntiles; ++kt) {
        __syncthreads();   // drains tile kt's GLOADs (issued one compute-phase ago)

        if (kt + 1 < ntiles) {   // prefetch tile kt+1 into the other buffer
            const unsigned short* kb2 = kbase + (size_t)(kt + 1) * 64 * DH;
            const unsigned short* vb2 = vbase + (size_t)(kt + 1) * 64;
            unsigned short* dst = lds + ((kt + 1) & 1) * 16384;
            #pragma unroll
            for (int i = 0; i < 4; ++i) {
                int cid = i * 256 + tid;
                GLOAD(kb2 + ksrc[i], dst + (size_t)cid * 8);
                GLOAD(vb2 + vsrc[i], dst + 8192 + (size_t)cid * 8);
            }
        }

        const unsigned short* Ks = lds + (kt & 1) * 16384;
        const unsigned short* Vs = Ks + 8192;

        // S = Q K^T : per wave 32 q-rows x 64 keys; K frags shared across rb
        floatx4 sv[2][4] = {};
        #pragma unroll
        for (int kc = 0; kc < 4; ++kc) {
            short8 kf[4];
            #pragma unroll
            for (int nb = 0; nb < 4; ++nb)
                kf[nb] = *(const short8*)&Ks[(kc * 256 + swz(nb * 16 + (l & 15), l >> 4)) * 8];
            #pragma unroll
            for (int rb = 0; rb < 2; ++rb)
                #pragma unroll
                for (int nb = 0; nb < 4; ++nb)
                    sv[rb][nb] = __builtin_amdgcn_mfma_f32_16x16x32_bf16(
                        qf[rb][kc], kf[nb], sv[rb][nb], 0, 0, 0);
        }

        // softmax (no max-subtraction) + P -> per-wave 16-row slab, rb serial
        const int valid = slen - kt * 64;
        short8 pa[2][2];
        #pragma unroll
        for (int rb = 0; rb < 2; ++rb) {
            if (valid >= 64) {
                #pragma unroll
                for (int nb = 0; nb < 4; ++nb)
                    #pragma unroll
                    for (int r = 0; r < 4; ++r)
                        sv[rb][nb][r] = exp2f(sv[rb][nb][r]);
            } else {
                #pragma unroll
                for (int nb = 0; nb < 4; ++nb) {
                    const int key = nb * 16 + (l & 15);
                    #pragma unroll
                    for (int r = 0; r < 4; ++r)
                        sv[rb][nb][r] = (key < valid) ? exp2f(sv[rb][nb][r]) : 0.0f;
                }
            }
            #pragma unroll
            for (int r = 0; r < 4; ++r)
                lsum[rb][r] += sv[rb][0][r] + sv[rb][1][r] + sv[rb][2][r] + sv[rb][3][r];
            #pragma unroll
            for (int nb = 0; nb < 4; ++nb)
                #pragma unroll
                for (int r = 0; r < 4; r += 2) {
                    union { __hip_bfloat162 v; ushort2 u; } cv;
                    cv.v = __float22bfloat162_rn(
                        make_float2(sv[rb][nb][r], sv[rb][nb][r + 1]));
                    const int rowb = (l >> 4) * 4 + r;
                    Psw[rowb * 72 + nb * 16 + (l & 15)]       = cv.u.x;
                    Psw[(rowb + 1) * 72 + nb * 16 + (l & 15)] = cv.u.y;
                }
            #pragma unroll
            for (int ks = 0; ks < 2; ++ks)
                pa[rb][ks] = *(const short8*)&Psw[(l & 15) * 72 + ks * 32 + (l >> 4) * 8];
        }

        // O += P V : V frags shared across rb
        #pragma unroll
        for (int ks = 0; ks < 2; ++ks)
            #pragma unroll
            for (int nb2 = 0; nb2 < 8; ++nb2) {
                short8 vf = *(const short8*)&Vs[(ks * 512 + swz(nb2 * 16 + (l & 15), l >> 4)) * 8];
                #pragma unroll
                for (int rb = 0; rb < 2; ++rb)
                    acc[rb][nb2] = __builtin_amdgcn_mfma_f32_16x16x32_bf16(
                        pa[rb][ks], vf, acc[rb][nb2], 0, 0, 0);
            }
    }

    #pragma unroll
    for (int rb = 0; rb < 2; ++rb) {
        float rl[4];
        #pragma unroll
        for (int r = 0; r < 4; ++r) {
            float s = lsum[rb][r];
            #pragma unroll
            for (int mm = 1; mm < 16; mm <<= 1) s += __shfl_xor(s, mm, 64);
            rl[r] = 1.0f / s;
        }
        #pragma unroll
        for (int nb2 = 0; nb2 < 8; ++nb2) {
            const int col = h * DH + nb2 * 16 + (l & 15);
            #pragma unroll
            for (int r = 0; r < 4; ++r) {
                const int srow = s0 + w * 32 + rb * 16 + (l >> 4) * 4 + r;
                out[((size_t)b * SS + srow) * CC + col] = f2bf(acc[rb][nb2][r] * rl[r]);
            }
        }
    }
}

// ---------------------------------------------------------------------------
extern "C" void kernel_launch(void* const* d_in, const int* in_sizes, int n_in,
                              void* d_out, int out_size, void* d_ws, size_t ws_size,
                              hipStream_t stream) {
    const float* x          = (const float*)d_in[0];
    const int*   seq_lens   = (const int*)d_in[1];
    const int*   grid_sizes = (const int*)d_in[2];
    const float* freqs      = (const float*)d_in[3];
    const float* Wq         = (const float*)d_in[4];
    const float* bq         = (const float*)d_in[5];
    const float* Wk         = (const float*)d_in[6];
    const float* bk         = (const float*)d_in[7];
    const float* Wv         = (const float*)d_in[8];
    const float* bv         = (const float*)d_in[9];
    const float* Wo         = (const float*)d_in[10];
    const float* bo         = (const float*)d_in[11];
    const float* nqw        = (const float*)d_in[12];
    const float* nkw        = (const float*)d_in[13];
    float* out = (float*)d_out;

    const size_t TE = (size_t)NTOK * CC;   // 9,437,184 (= 4*WE)
    unsigned short* xb  = (unsigned short*)d_ws;   // xb..wob contiguous
    unsigned short* wqb = xb + TE;
    unsigned short* wkb = wqb + WE;
    unsigned short* wvb = wkb + WE;
    unsigned short* wob = wvb + WE;
    unsigned short* qb  = wob + WE;
    unsigned short* kb  = qb + TE;
    unsigned short* vtb = kb + TE;
    unsigned short* ab  = vtb + TE;
    float2* tab = (float2*)(ab + TE);      // 3072*64 float2 = 1.5 MB

    cast_all<<<dim3(WE / 1024, 8), 256, 0, stream>>>(x, Wq, Wk, Wv, Wo, xb);
    rope_table<<<dim3(SS * 64 / 256), 256, 0, stream>>>(freqs, grid_sizes, tab);

    qkv_gemm<<<dim3(NTOK / 128, 36), 256, 0, stream>>>(
        xb, wqb, wkb, wvb, bq, bk, bv, qb, kb, vtb);

    norm_rope<<<dim3(2 * NTOK), 256, 0, stream>>>(qb, kb, nqw, nkw, tab);

    flash_attn_mfma<<<dim3(NB * NH * (SS / 128)), 256, 0, stream>>>(qb, kb, vtb, seq_lens, ab);

    gemm_o<<<dim3(NTOK / 128, CC / 128), 256, 0, stream>>>(ab, wob, bo, out);
}